// Round 4
// baseline (676.697 us; speedup 1.0000x reference)
//
#include <hip/hip_runtime.h>
#include <stdint.h>

#define H_DIM 768
#define N_SUP 32768
#define Q_QRY 32768
#define C_CLS 10
#define M_TOT 65536   // spans total; also token count
#define KG 768        // GEMM K
#define NT 12         // K tiles of 64
#define NBUCK 1024

typedef __bf16 bf16x8 __attribute__((ext_vector_type(8)));
typedef float f32x4 __attribute__((ext_vector_type(4)));
typedef __attribute__((address_space(3))) void lds_void;
typedef const __attribute__((address_space(1))) void g_void;

__device__ __forceinline__ ushort f2bf(float f) {
  union { float f; uint32_t u; } v; v.f = f;
  uint32_t r = (v.u + 0x7FFFu + ((v.u >> 16) & 1u)) >> 16;
  return (ushort)r;
}
__device__ __forceinline__ float bf2f(ushort h) {
  union { uint32_t u; float f; } v; v.u = ((uint32_t)h) << 16; return v.f;
}
__device__ __forceinline__ float gelu_f(float x) {
  return 0.5f * x * (1.0f + erff(x * 0.70710678118654752f));
}

// ---------------- token_emb fp32 -> bf16 ----------------
__global__ void cvt_kernel(const float* __restrict__ te, ushort* __restrict__ tb) {
  size_t i = (((size_t)blockIdx.x * 256) + threadIdx.x) * 8;
  float4 v0 = *(const float4*)(te + i);
  float4 v1 = *(const float4*)(te + i + 4);
  ushort4 o0, o1;
  o0.x = f2bf(v0.x); o0.y = f2bf(v0.y); o0.z = f2bf(v0.z); o0.w = f2bf(v0.w);
  o1.x = f2bf(v1.x); o1.y = f2bf(v1.y); o1.z = f2bf(v1.z); o1.w = f2bf(v1.w);
  *(ushort4*)(tb + i) = o0;
  *(ushort4*)(tb + i + 4) = o1;
}

// ---------------- Bt[n][k] = Wall^T ----------------
__global__ void wt2_kernel(const float* __restrict__ W, ushort* __restrict__ Bt) {
  int idx = blockIdx.x * 256 + threadIdx.x;   // < 2304*768
  int n = idx / KG, k = idx - n * KG;
  int blk = n / H_DIM;
  int c = n - blk * H_DIM;
  Bt[idx] = f2bf(W[(size_t)(blk * H_DIM + k) * H_DIM + c]);
}

// ---------------- span sort by start: hist / prefix / scatter ----------------
__global__ void hist_kernel(const int* __restrict__ spS, const int* __restrict__ spQ,
                            int* __restrict__ hist) {
  __shared__ int lh[NBUCK];
  int t = threadIdx.x;
  for (int i = t; i < NBUCK; i += 256) lh[i] = 0;
  __syncthreads();
  for (int i = blockIdx.x * 256 + t; i < M_TOT; i += gridDim.x * 256) {
    int s = (i < N_SUP) ? spS[2 * i] : spQ[2 * (i - N_SUP)];
    atomicAdd(&lh[s >> 6], 1);
  }
  __syncthreads();
  for (int i = t; i < NBUCK; i += 256) if (lh[i]) atomicAdd(&hist[i], lh[i]);
}

__global__ void prefix_kernel(const int* __restrict__ hist, int* __restrict__ cursor) {
  __shared__ int tmp[NBUCK];
  int t = threadIdx.x;
  int v = hist[t];
  tmp[t] = v;
  __syncthreads();
  for (int off = 1; off < NBUCK; off <<= 1) {
    int add = (t >= off) ? tmp[t - off] : 0;
    __syncthreads();
    tmp[t] += add;
    __syncthreads();
  }
  cursor[t] = tmp[t] - v;   // exclusive prefix
}

__global__ void scatter_kernel(const int* __restrict__ spS, const int* __restrict__ spQ,
                               int* __restrict__ cursor, int2* __restrict__ sorted) {
  for (int i = blockIdx.x * 256 + threadIdx.x; i < M_TOT; i += gridDim.x * 256) {
    int s, e;
    if (i < N_SUP) { s = spS[2 * i]; e = spS[2 * i + 1]; }
    else           { int w = i - N_SUP; s = spQ[2 * w]; e = spQ[2 * w + 1]; }
    int pos = atomicAdd(&cursor[s >> 6], 1);
    int2 rec; rec.x = s; rec.y = (i << 5) | (e - s);
    sorted[pos] = rec;
  }
}

// ---------------- 256x256 8-wave 2-phase GEMM: [P|Q|R] planes = te_bf @ Wall ----------------
// R2 grid (2304 blocks, XCD swizzle) + merged phases (4 barriers/tile) +
// swapped-operand MFMA -> cvt_pk + dwordx2 epilogue -> P/Q/R plane split.
__global__ __launch_bounds__(512, 2) void gemm8(const ushort* __restrict__ A,
                                                const ushort* __restrict__ Bt,
                                                ushort* __restrict__ Pp,
                                                ushort* __restrict__ Qp,
                                                ushort* __restrict__ Rp) {
  __shared__ ushort lds[65536];  // 128 KB
  char* ldsc = (char*)lds;

  int orig = blockIdx.x;
  int wg = (orig & 7) * 288 + (orig >> 3);   // nwg=2304 = 8*288, bijective
  int rowT = wg / 9, colT = wg - rowT * 9;
  int m0 = rowT * 256;

  int tid = threadIdx.x;
  int lane = tid & 63, wave = tid >> 6;
  int wr = wave >> 2, wc = wave & 3;         // 2x4 wave grid; per-wave C = 128x64
  int l15 = lane & 15, l4 = lane >> 4;

  // staging: linear LDS dest, inverse-swizzled global src
  int row0 = tid >> 2;                        // 0..127 (L=0); L=1 adds 128
  int ss = (tid & 3) ^ ((row0 >> 1) & 3);
  size_t eA0 = (size_t)(m0 + row0) * KG + ss * 8;
  size_t eA1 = (size_t)(m0 + row0 + 128) * KG + ss * 8;
  size_t eB0 = (size_t)(colT * 256 + row0) * KG + ss * 8;
  size_t eB1 = (size_t)(colT * 256 + row0 + 128) * KG + ss * 8;

  int aoff[8], boff[4];
#pragma unroll
  for (int m = 0; m < 8; ++m) {
    int r = wr * 128 + m * 16 + l15;
    aoff[m] = r * 64 + ((l4 ^ ((r >> 1) & 3)) << 4);
  }
#pragma unroll
  for (int n = 0; n < 4; ++n) {
    int r = wc * 64 + n * 16 + l15;
    boff[n] = r * 64 + ((l4 ^ ((r >> 1) & 3)) << 4);
  }

  f32x4 acc[8][4];
#pragma unroll
  for (int m = 0; m < 8; ++m)
#pragma unroll
    for (int n = 0; n < 4; ++n) acc[m][n] = (f32x4){0.f, 0.f, 0.f, 0.f};

#define SLOT_A(kh, db) (ldsc + ((kh) * 2 + (db)) * 16384)
#define SLOT_B(kh, db) (ldsc + 65536 + ((kh) * 2 + (db)) * 16384)
// one stage group = 4 global_load_lds per thread (A half + B half of one kh)
#define SAB(kOff, kh, db) do { \
    char* _da = SLOT_A(kh, db) + wave * 1024; \
    char* _db = SLOT_B(kh, db) + wave * 1024; \
    size_t _k = (size_t)(kOff) + (kh) * 32; \
    __builtin_amdgcn_global_load_lds((g_void*)(A + eA0 + _k), (lds_void*)_da, 16, 0, 0); \
    __builtin_amdgcn_global_load_lds((g_void*)(A + eA1 + _k), (lds_void*)(_da + 8192), 16, 0, 0); \
    __builtin_amdgcn_global_load_lds((g_void*)(Bt + eB0 + _k), (lds_void*)_db, 16, 0, 0); \
    __builtin_amdgcn_global_load_lds((g_void*)(Bt + eB1 + _k), (lds_void*)(_db + 8192), 16, 0, 0); \
  } while (0)
#define LDA8(base) do { _Pragma("unroll") for (int m = 0; m < 8; ++m) \
    af[m] = *reinterpret_cast<const bf16x8*>((base) + aoff[m]); } while (0)
#define LDB4(base) do { _Pragma("unroll") for (int n = 0; n < 4; ++n) \
    bf[n] = *reinterpret_cast<const bf16x8*>((base) + boff[n]); } while (0)
// swapped operands: lane holds C[row=l15-based][4 consecutive cols at l4*4]
#define MFMA32() do { _Pragma("unroll") for (int m = 0; m < 8; ++m) \
  _Pragma("unroll") for (int n = 0; n < 4; ++n) \
    acc[m][n] = __builtin_amdgcn_mfma_f32_16x16x32_bf16(bf[n], af[m], acc[m][n], 0, 0, 0); \
  } while (0)
#define BARX() __builtin_amdgcn_s_barrier()
#define LGKM0() asm volatile("s_waitcnt lgkmcnt(0)" ::: "memory")
#define VM8() asm volatile("s_waitcnt vmcnt(8)" ::: "memory")

  // prologue: kh0(0), kh1(0), kh0(1); VM8 drains kh0(0)
  SAB(0, 0, 0);
  SAB(0, 1, 0);
  SAB(64, 0, 1);
  VM8();
  BARX();

  bf16x8 af[8], bf[4];
  for (int t = 0; t < NT; ++t) {
    int d = t & 1, nd = d ^ 1;
    int k1 = ((t + 1 < NT) ? t + 1 : NT - 1) * 64;  // clamped: writes dead slots only
    int k2 = ((t + 2 < NT) ? t + 2 : NT - 1) * 64;
    // Phase A: kh0
    LDA8(SLOT_A(0, d)); LDB4(SLOT_B(0, d));
    SAB(k1, 1, nd);
    BARX(); LGKM0();
    __builtin_amdgcn_s_setprio(1); MFMA32(); __builtin_amdgcn_s_setprio(0);
    VM8();   // drains kh1(t) group -> ready for Phase B
    BARX();
    // Phase B: kh1
    LDA8(SLOT_A(1, d)); LDB4(SLOT_B(1, d));
    SAB(k2, 0, d);
    BARX(); LGKM0();
    __builtin_amdgcn_s_setprio(1); MFMA32(); __builtin_amdgcn_s_setprio(0);
    VM8();   // drains kh0(t+1) group -> ready for next Phase A
    BARX();
  }
  asm volatile("s_waitcnt vmcnt(0)" ::: "memory");

  // epilogue: plane-split stores (each colT maps to exactly one plane)
  {
    int plane = colT / 3;
    int pcol0 = colT * 256 - plane * 768;
    ushort* base = (plane == 0) ? Pp : ((plane == 1) ? Qp : Rp);
#pragma unroll
    for (int m = 0; m < 8; ++m) {
      int row = m0 + wr * 128 + m * 16 + l15;
#pragma unroll
      for (int n = 0; n < 4; ++n) {
        int col = pcol0 + wc * 64 + n * 16 + l4 * 4;
        uint32_t lo, hi;
        asm("v_cvt_pk_bf16_f32 %0, %1, %2" : "=v"(lo) : "v"(acc[m][n][0]), "v"(acc[m][n][1]));
        asm("v_cvt_pk_bf16_f32 %0, %1, %2" : "=v"(hi) : "v"(acc[m][n][2]), "v"(acc[m][n][3]));
        uint2 val; val.x = lo; val.y = hi;
        *reinterpret_cast<uint2*>(base + (size_t)row * H_DIM + col) = val;
      }
    }
  }
#undef SLOT_A
#undef SLOT_B
#undef SAB
#undef LDA8
#undef LDB4
#undef MFMA32
}

// ---------------- span combine (sorted order): emb[orig] = gelu(P[s]+Q[e-1]+meanR+b) ----------------
__global__ void combine2(const ushort* __restrict__ Pp, const ushort* __restrict__ Qp,
                         const ushort* __restrict__ Rp, const int2* __restrict__ sorted,
                         const float* __restrict__ bias, ushort* __restrict__ emb) {
  int wid = (int)((((size_t)blockIdx.x * blockDim.x) + threadIdx.x) >> 6);
  int lane = threadIdx.x & 63;
  if (wid >= M_TOT) return;
  int2 rec = sorted[wid];
  int s = rec.x;
  int len = rec.y & 31;
  int orig = rec.y >> 5;
  int e = s + len;
  float inv = 1.0f / (float)len;

  float acc0[3][4], accr[3][4];
  const ushort* Pr = Pp + (size_t)s * H_DIM;
  const ushort* Qr = Qp + (size_t)(e - 1) * H_DIM;
#pragma unroll
  for (int c = 0; c < 3; ++c) {
    int h = c * 256 + lane * 4;
    ushort4 p = *(const ushort4*)(Pr + h);
    ushort4 q = *(const ushort4*)(Qr + h);
    acc0[c][0] = bf2f(p.x) + bf2f(q.x);
    acc0[c][1] = bf2f(p.y) + bf2f(q.y);
    acc0[c][2] = bf2f(p.z) + bf2f(q.z);
    acc0[c][3] = bf2f(p.w) + bf2f(q.w);
    accr[c][0] = accr[c][1] = accr[c][2] = accr[c][3] = 0.f;
  }
  for (int r = s; r < e; ++r) {
    const ushort* Rr = Rp + (size_t)r * H_DIM;
#pragma unroll
    for (int c = 0; c < 3; ++c) {
      int h = c * 256 + lane * 4;
      ushort4 rv = *(const ushort4*)(Rr + h);
      accr[c][0] += bf2f(rv.x); accr[c][1] += bf2f(rv.y);
      accr[c][2] += bf2f(rv.z); accr[c][3] += bf2f(rv.w);
    }
  }
  ushort* er = emb + (size_t)orig * H_DIM;
#pragma unroll
  for (int c = 0; c < 3; ++c) {
    int h = c * 256 + lane * 4;
    float4 bv = *(const float4*)(bias + h);
    ushort4 o;
    o.x = f2bf(gelu_f(acc0[c][0] + accr[c][0] * inv + bv.x));
    o.y = f2bf(gelu_f(acc0[c][1] + accr[c][1] * inv + bv.y));
    o.z = f2bf(gelu_f(acc0[c][2] + accr[c][2] * inv + bv.z));
    o.w = f2bf(gelu_f(acc0[c][3] + accr[c][3] * inv + bv.w));
    *(ushort4*)(er + h) = o;
  }
}

// ---------------- proto accumulation ----------------
__global__ void proto_accum(const ushort* __restrict__ supEmb, const int* __restrict__ labels,
                            float* __restrict__ pSum, float* __restrict__ pCnt) {
  __shared__ float ls[C_CLS * H_DIM];
  __shared__ int lc[C_CLS];
  int t = threadIdx.x;
  for (int i = t; i < C_CLS * H_DIM; i += 256) ls[i] = 0.f;
  if (t < C_CLS) lc[t] = 0;
  __syncthreads();
  int base = blockIdx.x * 128;
  for (int si = 0; si < 128; ++si) {
    int sp = base + si;
    int lab = labels[sp];
    const ushort* er = supEmb + (size_t)sp * H_DIM;
#pragma unroll
    for (int j = 0; j < 3; ++j) {
      int c = t + j * 256;
      ls[lab * H_DIM + c] += bf2f(er[c]);
    }
    if (t == 0) lc[lab]++;
  }
  __syncthreads();
  for (int i = t; i < C_CLS * H_DIM; i += 256) atomicAdd(&pSum[i], ls[i]);
  if (t < C_CLS) atomicAdd(&pCnt[t], (float)lc[t]);
}

// ---------------- proto normalize (1 block) ----------------
__global__ void proto_norm(const float* __restrict__ pSum, const float* __restrict__ pCnt,
                           float* __restrict__ pN) {
  __shared__ float red[4];
  int t = threadIdx.x, lane = t & 63, wave = t >> 6;
  for (int c = 0; c < C_CLS; ++c) {
    float cnt = pCnt[c];
    float x[3];
#pragma unroll
    for (int j = 0; j < 3; ++j) {
      int h = t + j * 256;
      float v;
      if (cnt > 0.5f) v = pSum[c * H_DIM + h] / cnt;
      else {
        float gs = 0.f;
        for (int cc = 0; cc < C_CLS; ++cc) gs += pSum[cc * H_DIM + h];
        v = gs / (float)N_SUP;
      }
      x[j] = v;
    }
    float ss = x[0] * x[0] + x[1] * x[1] + x[2] * x[2];
#pragma unroll
    for (int o = 32; o; o >>= 1) ss += __shfl_xor(ss, o);
    if (lane == 0) red[wave] = ss;
    __syncthreads();
    float tot = red[0] + red[1] + red[2] + red[3];
    float inv = 1.0f / fmaxf(sqrtf(tot), 1e-12f);
#pragma unroll
    for (int j = 0; j < 3; ++j) pN[c * H_DIM + t + j * 256] = x[j] * inv;
    __syncthreads();
  }
}

// ---------------- query sim ----------------
__global__ void sim_kernel(const ushort* __restrict__ emb, const float* __restrict__ pN,
                           float* __restrict__ out) {
  __shared__ float lp[C_CLS * H_DIM];
  int t = threadIdx.x;
  for (int i = t; i < C_CLS * H_DIM; i += 256) lp[i] = pN[i];
  __syncthreads();
  int lane = t & 63, wave = t >> 6;
  for (int row = blockIdx.x * 4 + wave; row < Q_QRY; row += gridDim.x * 4) {
    const ushort* qr = emb + (size_t)(N_SUP + row) * H_DIM;
    float dot[C_CLS] = {0, 0, 0, 0, 0, 0, 0, 0, 0, 0};
    float sq = 0.f;
#pragma unroll
    for (int j = 0; j < 12; ++j) {
      float v = bf2f(qr[lane + 64 * j]);
      sq += v * v;
#pragma unroll
      for (int p = 0; p < C_CLS; ++p) dot[p] += v * lp[p * H_DIM + lane + 64 * j];
    }
#pragma unroll
    for (int o = 32; o; o >>= 1) {
      sq += __shfl_xor(sq, o);
#pragma unroll
      for (int p = 0; p < C_CLS; ++p) dot[p] += __shfl_xor(dot[p], o);
    }
    if (lane == 0) {
      float inv = 1.0f / fmaxf(sqrtf(sq), 1e-12f);
      float* o = out + (size_t)row * (C_CLS + 1);
      o[0] = dot[0] * inv; o[1] = dot[1] * inv; o[2] = dot[2] * inv;
      o[3] = dot[3] * inv; o[4] = dot[4] * inv; o[5] = dot[5] * inv;
      o[6] = dot[6] * inv; o[7] = dot[7] * inv; o[8] = dot[8] * inv;
      o[9] = dot[9] * inv; o[10] = 0.5f;
    }
  }
}

extern "C" void kernel_launch(void* const* d_in, const int* in_sizes, int n_in,
                              void* d_out, int out_size, void* d_ws, size_t ws_size,
                              hipStream_t stream) {
  const float* token_emb = (const float*)d_in[0];
  const int*   spansS    = (const int*)d_in[1];
  const int*   labels    = (const int*)d_in[2];
  const int*   spansQ    = (const int*)d_in[3];
  const float* W         = (const float*)d_in[4];
  const float* b         = (const float*)d_in[5];
  float* out = (float*)d_out;

  char* ws = (char*)d_ws;
  size_t planeB = (size_t)M_TOT * H_DIM * 2;   // 100,663,296 each
  ushort* Pp   = (ushort*)ws;
  ushort* Qp   = (ushort*)(ws + planeB);
  ushort* Rp   = (ushort*)(ws + 2 * planeB);
  ushort* tebf = (ushort*)(ws + 3 * planeB);   // dead after gemm8
  ushort* emb  = tebf;                          // alias (sequential lifetimes)
  ushort* Bt   = (ushort*)(ws + 4 * planeB);
  char*   tail = ws + 4 * planeB + (size_t)2304 * KG * 2;
  float*  pSum = (float*)tail;                                  // 7680 f
  float*  pCnt = pSum + C_CLS * H_DIM;                          // 64 f
  float*  pN   = pCnt + 64;                                     // 7680 f
  int*    hist = (int*)(pN + C_CLS * H_DIM);                    // 1024
  int*    cursor = hist + NBUCK;                                // 1024
  int2*   sorted = (int2*)(cursor + NBUCK);                     // 65536 int2

  hipMemsetAsync(pSum, 0, (C_CLS * H_DIM + 64) * sizeof(float), stream);
  hipMemsetAsync(hist, 0, NBUCK * sizeof(int), stream);
  cvt_kernel<<<24576, 256, 0, stream>>>(token_emb, tebf);
  wt2_kernel<<<6912, 256, 0, stream>>>(W, Bt);
  hist_kernel<<<64, 256, 0, stream>>>(spansS, spansQ, hist);
  prefix_kernel<<<1, NBUCK, 0, stream>>>(hist, cursor);
  scatter_kernel<<<64, 256, 0, stream>>>(spansS, spansQ, cursor, sorted);
  gemm8<<<2304, 512, 0, stream>>>(tebf, Bt, Pp, Qp, Rp);
  combine2<<<16384, 256, 0, stream>>>(Pp, Qp, Rp, sorted, b, emb);
  proto_accum<<<N_SUP / 128, 256, 0, stream>>>(emb, labels, pSum, pCnt);
  proto_norm<<<1, 256, 0, stream>>>(pSum, pCnt, pN);
  sim_kernel<<<512, 256, 0, stream>>>(emb, pN, out);
}